// Round 7
// baseline (505.171 us; speedup 1.0000x reference)
//
#include <hip/hip_runtime.h>
#include <math.h>

// GEVCanonicalLoss (xi=0.5): mean over 8192x8192 of l + ent
//   u    = min((1 + 0.5*x)^-2 with base clamp, 13.815511)   [exp/log round-trip elided]
//   gi   = 2*exp(-u)/sqrt(u) - 2*sqrt(pi)*erfc(sqrt(u))
//   l    = gi - t*max(x, -2);  ent = t ? ent1 : ent0  (t in {0,1})
// erfc via Abramowitz-Stegun 7.1.26 (|err| <= 1.5e-7), sharing exp(-u).
//
// R6: split read paths. Normal (L1) path caps at 3.33 TB/s (R2), nt path at
// ~4.2 TB/s (R4/R5, MLP-independent). Caps are at different pipeline stages,
// so route x through the normal path and t through nt — each carries half
// the traffic, aggregate target ~6 TB/s.

static constexpr int BLOCK  = 256;
static constexpr int GRID   = 2048;
static constexpr int UNROLL = 4;

typedef float vfloat4 __attribute__((ext_vector_type(4)));
typedef int   vint4   __attribute__((ext_vector_type(4)));

__device__ __forceinline__ float gev_elem(float x, int t, float ent0, float ent1)
{
    const float SQRTPI = 1.7724538509055160273f;
    const float LOG2E  = 1.4426950408889634f;
    const float UMAX   = 13.815511f;            // -logf(1e-6f)
    const float P  = 0.3275911f;
    const float A1 = 0.254829592f;
    const float A2 = -0.284496736f;
    const float A3 = 1.421413741f;
    const float A4 = -1.453152027f;
    const float A5 = 1.061405429f;

    float base = fmaxf(fmaf(0.5f, x, 1.0f), 1e-6f);
    float rb   = __builtin_amdgcn_rcpf(base);
    float u    = fminf(rb * rb, UMAX);

    float s  = __builtin_amdgcn_sqrtf(u);
    float rs = __builtin_amdgcn_rsqf(u);           // 1/sqrt(u)
    float e  = __builtin_amdgcn_exp2f(-u * LOG2E); // exp(-u)

    float td = __builtin_amdgcn_rcpf(fmaf(P, s, 1.0f));
    float p  = fmaf(td, A5, A4);
    p = fmaf(td, p, A3);
    p = fmaf(td, p, A2);
    p = fmaf(td, p, A1);
    p = p * td;                                    // erfc(s)*exp(u)

    float inner = fmaf(-SQRTPI, p, rs);
    float gi = (e + e) * inner;                    // gammainc_neg(u)

    return gi + (t ? (ent1 - fmaxf(x, -2.0f)) : ent0);
}

__global__ __launch_bounds__(BLOCK) void gev_partial_kernel(
    const vfloat4* __restrict__ x4,
    const vint4*  __restrict__ t4,
    double*      __restrict__ partial,
    long long n4)
{
    const float SQRTPI = 1.7724538509055160273f;
    const float ent0 = 2.0f * (SQRTPI * erfcf(sqrtf(-logf(1e-6f))));
    const float ent1 = 2.0f * (SQRTPI * erfcf(sqrtf(-logf(1.0f - 1e-6f))) - 1.0f);

    const long long chunk   = (long long)BLOCK * UNROLL;   // vfloat4s per block-iter
    const long long nchunks = n4 / chunk;

    double sum = 0.0;

    for (long long c = blockIdx.x; c < nchunks; c += gridDim.x) {
        long long base = c * chunk + threadIdx.x;

        vfloat4 xv[UNROLL];
        vint4   tv[UNROLL];
        // interleave: x via normal (L1) path, t via nt (L2) path — both
        // pipeline stages fill concurrently
#pragma unroll
        for (int j = 0; j < UNROLL; ++j) {
            xv[j] = x4[base + (long long)j * BLOCK];
            tv[j] = __builtin_nontemporal_load(&t4[base + (long long)j * BLOCK]);
        }

        float vsum = 0.0f;
#pragma unroll
        for (int j = 0; j < UNROLL; ++j) {
            vsum += gev_elem(xv[j].x, tv[j].x, ent0, ent1);
            vsum += gev_elem(xv[j].y, tv[j].y, ent0, ent1);
            vsum += gev_elem(xv[j].z, tv[j].z, ent0, ent1);
            vsum += gev_elem(xv[j].w, tv[j].w, ent0, ent1);
        }
        sum += (double)vsum;
    }

    // tail (n4 not divisible by chunk): block 0 mops up, strided
    long long done = nchunks * chunk;
    if (blockIdx.x == 0) {
        for (long long i = done + threadIdx.x; i < n4; i += BLOCK) {
            vfloat4 xv = x4[i];
            vint4   tv = t4[i];
            float vsum = gev_elem(xv.x, tv.x, ent0, ent1)
                       + gev_elem(xv.y, tv.y, ent0, ent1)
                       + gev_elem(xv.z, tv.z, ent0, ent1)
                       + gev_elem(xv.w, tv.w, ent0, ent1);
            sum += (double)vsum;
        }
    }

    // wave reduce (64 lanes)
    for (int off = 32; off > 0; off >>= 1)
        sum += __shfl_down(sum, off);

    __shared__ double lds[BLOCK / 64];
    int wave = threadIdx.x >> 6;
    int lane = threadIdx.x & 63;
    if (lane == 0) lds[wave] = sum;
    __syncthreads();
    if (threadIdx.x == 0) {
        double tot = 0.0;
        for (int wv = 0; wv < BLOCK / 64; ++wv) tot += lds[wv];
        partial[blockIdx.x] = tot;
    }
}

__global__ __launch_bounds__(BLOCK) void gev_final_kernel(
    const double* __restrict__ partial,
    float*        __restrict__ out,
    int nblocks,
    double inv_n)
{
    double sum = 0.0;
    for (int i = threadIdx.x; i < nblocks; i += blockDim.x)
        sum += partial[i];

    for (int off = 32; off > 0; off >>= 1)
        sum += __shfl_down(sum, off);

    __shared__ double lds[BLOCK / 64];
    int wave = threadIdx.x >> 6;
    int lane = threadIdx.x & 63;
    if (lane == 0) lds[wave] = sum;
    __syncthreads();
    if (threadIdx.x == 0) {
        double tot = 0.0;
        for (int wv = 0; wv < BLOCK / 64; ++wv) tot += lds[wv];
        out[0] = (float)(tot * inv_n);
    }
}

extern "C" void kernel_launch(void* const* d_in, const int* in_sizes, int n_in,
                              void* d_out, int out_size, void* d_ws, size_t ws_size,
                              hipStream_t stream)
{
    const float* x = (const float*)d_in[0];
    const int*   t = (const int*)d_in[1];
    float* out = (float*)d_out;

    long long n  = (long long)in_sizes[0];   // 8192*8192, divisible by 4
    long long n4 = n >> 2;

    double* partial = (double*)d_ws;

    gev_partial_kernel<<<GRID, BLOCK, 0, stream>>>(
        (const vfloat4*)x, (const vint4*)t, partial, n4);

    gev_final_kernel<<<1, BLOCK, 0, stream>>>(
        partial, out, GRID, 1.0 / (double)n);
}

// Round 8
// 477.941 us; speedup vs baseline: 1.0570x; 1.0570x over previous
//
#include <hip/hip_runtime.h>
#include <math.h>

// GEVCanonicalLoss (xi=0.5): mean over 8192x8192 of l + ent
//   u    = min((1 + 0.5*x)^-2 with base clamp, 13.815511)   [exp/log round-trip elided]
//   gi   = 2*exp(-u)/sqrt(u) - 2*sqrt(pi)*erfc(sqrt(u))
//   l    = gi - t*max(x, -2);  ent = t ? ent1 : ent0  (t in {0,1})
// erfc via Abramowitz-Stegun 7.1.26 (|err| <= 1.5e-7), sharing exp(-u).
//
// R7: x via nt VGPR loads (R5's 4.2 TB/s path) + t via global_load_lds DMA
// (untested independent read path; m97 staged at ~6.7 TB/s through it).
// R6 taught us mixing normal+nt serializes at the slower cap (in-order wave
// issue); DMA-to-LDS doesn't hold a VGPR return slot, so the hazard differs.
// Each thread reads back its own wave's staged lanes -> no __syncthreads,
// just s_waitcnt vmcnt(0).

static constexpr int BLOCK  = 256;
static constexpr int GRID   = 2048;
static constexpr int UNROLL = 4;

typedef float vfloat4 __attribute__((ext_vector_type(4)));
typedef int   vint4   __attribute__((ext_vector_type(4)));

typedef __attribute__((address_space(1))) void gvoid_t;
typedef __attribute__((address_space(3))) void svoid_t;

__device__ __forceinline__ float gev_elem(float x, int t, float ent0, float ent1)
{
    const float SQRTPI = 1.7724538509055160273f;
    const float LOG2E  = 1.4426950408889634f;
    const float UMAX   = 13.815511f;            // -logf(1e-6f)
    const float P  = 0.3275911f;
    const float A1 = 0.254829592f;
    const float A2 = -0.284496736f;
    const float A3 = 1.421413741f;
    const float A4 = -1.453152027f;
    const float A5 = 1.061405429f;

    float base = fmaxf(fmaf(0.5f, x, 1.0f), 1e-6f);
    float rb   = __builtin_amdgcn_rcpf(base);
    float u    = fminf(rb * rb, UMAX);

    float s  = __builtin_amdgcn_sqrtf(u);
    float rs = __builtin_amdgcn_rsqf(u);           // 1/sqrt(u)
    float e  = __builtin_amdgcn_exp2f(-u * LOG2E); // exp(-u)

    float td = __builtin_amdgcn_rcpf(fmaf(P, s, 1.0f));
    float p  = fmaf(td, A5, A4);
    p = fmaf(td, p, A3);
    p = fmaf(td, p, A2);
    p = fmaf(td, p, A1);
    p = p * td;                                    // erfc(s)*exp(u)

    float inner = fmaf(-SQRTPI, p, rs);
    float gi = (e + e) * inner;                    // gammainc_neg(u)

    return gi + (t ? (ent1 - fmaxf(x, -2.0f)) : ent0);
}

__global__ __launch_bounds__(BLOCK) void gev_partial_kernel(
    const vfloat4* __restrict__ x4,
    const vint4*  __restrict__ t4,
    double*      __restrict__ partial,
    long long n4)
{
    const float SQRTPI = 1.7724538509055160273f;
    const float ent0 = 2.0f * (SQRTPI * erfcf(sqrtf(-logf(1e-6f))));
    const float ent1 = 2.0f * (SQRTPI * erfcf(sqrtf(-logf(1.0f - 1e-6f))) - 1.0f);

    // t staging: each wave's DMA lands at uniform base + lane*16, i.e. slot[tid]
    __shared__ vint4 tbuf[UNROLL][BLOCK];

    const long long chunk   = (long long)BLOCK * UNROLL;   // vfloat4s per block-iter
    const long long nchunks = n4 / chunk;                  // 16384 at n=2^26

    const int tid      = threadIdx.x;
    const int wavebase = (tid >> 6) << 6;                  // wave-uniform

    double sum = 0.0;

    for (long long c = blockIdx.x; c < nchunks; c += gridDim.x) {
        long long base = c * chunk + tid;

        vfloat4 xv[UNROLL];
        // issue all vmem back-to-back: x -> VGPR (nt), t -> LDS (DMA, nt aux)
#pragma unroll
        for (int j = 0; j < UNROLL; ++j) {
            xv[j] = __builtin_nontemporal_load(&x4[base + (long long)j * BLOCK]);
            __builtin_amdgcn_global_load_lds(
                (gvoid_t*)(&t4[base + (long long)j * BLOCK]),
                (svoid_t*)(&tbuf[j][wavebase]),
                16, 0, 2 /* nt */);
        }

        // drain vmem (covers both xv and the wave's own DMA writes to LDS);
        // no __syncthreads: each thread only reads its own lane's slot
        __asm__ volatile("s_waitcnt vmcnt(0)" ::: "memory");

        float vsum = 0.0f;
#pragma unroll
        for (int j = 0; j < UNROLL; ++j) {
            vint4 tv = tbuf[j][tid];
            vsum += gev_elem(xv[j].x, tv.x, ent0, ent1);
            vsum += gev_elem(xv[j].y, tv.y, ent0, ent1);
            vsum += gev_elem(xv[j].z, tv.z, ent0, ent1);
            vsum += gev_elem(xv[j].w, tv.w, ent0, ent1);
        }
        sum += (double)vsum;
    }

    // tail (n4 not divisible by chunk): block 0 mops up, strided
    long long done = nchunks * chunk;
    if (blockIdx.x == 0) {
        for (long long i = done + tid; i < n4; i += BLOCK) {
            vfloat4 xv = x4[i];
            vint4   tv = t4[i];
            float vsum = gev_elem(xv.x, tv.x, ent0, ent1)
                       + gev_elem(xv.y, tv.y, ent0, ent1)
                       + gev_elem(xv.z, tv.z, ent0, ent1)
                       + gev_elem(xv.w, tv.w, ent0, ent1);
            sum += (double)vsum;
        }
    }

    // wave reduce (64 lanes)
    for (int off = 32; off > 0; off >>= 1)
        sum += __shfl_down(sum, off);

    __shared__ double lds[BLOCK / 64];
    int wave = tid >> 6;
    int lane = tid & 63;
    if (lane == 0) lds[wave] = sum;
    __syncthreads();
    if (tid == 0) {
        double tot = 0.0;
        for (int wv = 0; wv < BLOCK / 64; ++wv) tot += lds[wv];
        partial[blockIdx.x] = tot;
    }
}

__global__ __launch_bounds__(BLOCK) void gev_final_kernel(
    const double* __restrict__ partial,
    float*        __restrict__ out,
    int nblocks,
    double inv_n)
{
    double sum = 0.0;
    for (int i = threadIdx.x; i < nblocks; i += blockDim.x)
        sum += partial[i];

    for (int off = 32; off > 0; off >>= 1)
        sum += __shfl_down(sum, off);

    __shared__ double lds[BLOCK / 64];
    int wave = threadIdx.x >> 6;
    int lane = threadIdx.x & 63;
    if (lane == 0) lds[wave] = sum;
    __syncthreads();
    if (threadIdx.x == 0) {
        double tot = 0.0;
        for (int wv = 0; wv < BLOCK / 64; ++wv) tot += lds[wv];
        out[0] = (float)(tot * inv_n);
    }
}

extern "C" void kernel_launch(void* const* d_in, const int* in_sizes, int n_in,
                              void* d_out, int out_size, void* d_ws, size_t ws_size,
                              hipStream_t stream)
{
    const float* x = (const float*)d_in[0];
    const int*   t = (const int*)d_in[1];
    float* out = (float*)d_out;

    long long n  = (long long)in_sizes[0];   // 8192*8192, divisible by 4
    long long n4 = n >> 2;

    double* partial = (double*)d_ws;

    gev_partial_kernel<<<GRID, BLOCK, 0, stream>>>(
        (const vfloat4*)x, (const vint4*)t, partial, n4);

    gev_final_kernel<<<1, BLOCK, 0, stream>>>(
        partial, out, GRID, 1.0 / (double)n);
}